// Round 1
// baseline (76.253 us; speedup 1.0000x reference)
//
#include <hip/hip_runtime.h>

// RedistributionNetwork: 128 sequential tridiagonal layers on [256,1024] f32 state.
// out[b,i] = sum over layers of 3-point stencil: a[i]*h[i-1] + b[i]*h[i] + c[i]*h[i+1]
// where a[l][i]=W[l,i,i-1], b[l][i]=W[l,i,i], c[l][i]=W[l,i,i+1] (off-band is exactly 0).

#define NXL 128   // layers
#define NYP 1024  // state width
#define NB  256   // batch
#define RPL 16    // rows per lane: 64 lanes * 16 = 1024

// ---------------- kernel 1: band extraction ----------------
// W: [NXL][NYP][NYP] f32, wb: [NXL][3][NYP] f32 (a, b, c diagonals)
__global__ __launch_bounds__(256) void extract_band(const float* __restrict__ W,
                                                    float* __restrict__ wb) {
    int idx = blockIdx.x * 256 + threadIdx.x;   // 0 .. NXL*NYP-1
    int l = idx >> 10;
    int i = idx & (NYP - 1);
    const float* row = W + ((size_t)l << 20) + ((size_t)i << 10);
    float a = (i > 0)       ? row[i - 1] : 0.0f;   // W[l,i,i-1]
    float b = row[i];                               // W[l,i,i]
    float c = (i < NYP - 1) ? row[i + 1] : 0.0f;   // W[l,i,i+1]
    float* dst = wb + (size_t)l * (3 * NYP);
    dst[i]            = a;
    dst[NYP + i]      = b;
    dst[2 * NYP + i]  = c;
}

// ---------------- kernel 2: banded propagation ----------------
struct Wl {
    float a[RPL], b[RPL], c[RPL];
};

__device__ __forceinline__ void load_layer(const float* __restrict__ wl, int i0, Wl& w) {
    const float4* pa = reinterpret_cast<const float4*>(wl + i0);
    const float4* pb = reinterpret_cast<const float4*>(wl + NYP + i0);
    const float4* pc = reinterpret_cast<const float4*>(wl + 2 * NYP + i0);
#pragma unroll
    for (int j = 0; j < RPL / 4; ++j) {
        reinterpret_cast<float4*>(w.a)[j] = pa[j];
        reinterpret_cast<float4*>(w.b)[j] = pb[j];
        reinterpret_cast<float4*>(w.c)[j] = pc[j];
    }
}

__device__ __forceinline__ void step(float h[RPL], const Wl& w) {
    // neighbor boundary values via in-wave shuffles (no LDS, no barriers)
    float left  = __shfl_up(h[RPL - 1], 1);  // h[i0-1]; lane0 garbage but a[0]=0
    float right = __shfl_down(h[0], 1);      // h[i0+RPL]; lane63 garbage but c[1023]=0
    float carry = left;                      // in-place sweep: carry = old h[j-1]
#pragma unroll
    for (int j = 0; j < RPL; ++j) {
        float orig = h[j];
        float hp = (j == RPL - 1) ? right : h[j + 1];
        h[j] = w.a[j] * carry + w.b[j] * orig + w.c[j] * hp;
        carry = orig;
    }
}

__global__ __launch_bounds__(64) void propagate(const float* __restrict__ x,
                                                const float* __restrict__ wb,
                                                float* __restrict__ out) {
    const int b = blockIdx.x;
    const int lane = threadIdx.x & 63;
    const int i0 = lane * RPL;

    float h[RPL];
    const float4* xb = reinterpret_cast<const float4*>(x + (size_t)b * NYP + i0);
#pragma unroll
    for (int j = 0; j < RPL / 4; ++j) {
        float4 v = xb[j];
        h[4 * j + 0] = v.x; h[4 * j + 1] = v.y;
        h[4 * j + 2] = v.z; h[4 * j + 3] = v.w;
    }

    Wl w0, w1;
    load_layer(wb, i0, w0);  // layer 0
#pragma unroll 1
    for (int l = 0; l < NXL; l += 2) {
        // prefetch next layer's weights before consuming current ones
        load_layer(wb + (size_t)(l + 1) * 3 * NYP, i0, w1);
        step(h, w0);
        if (l + 2 < NXL) load_layer(wb + (size_t)(l + 2) * 3 * NYP, i0, w0);
        step(h, w1);
    }

    float4* ob = reinterpret_cast<float4*>(out + (size_t)b * NYP + i0);
#pragma unroll
    for (int j = 0; j < RPL / 4; ++j) {
        ob[j] = make_float4(h[4 * j + 0], h[4 * j + 1], h[4 * j + 2], h[4 * j + 3]);
    }
}

// ---------------- fallback: direct scattered weight reads (if ws too small) ----------------
__device__ __forceinline__ void load_layer_direct(const float* __restrict__ Wlayer, int i0, Wl& w) {
#pragma unroll
    for (int j = 0; j < RPL; ++j) {
        int i = i0 + j;
        const float* row = Wlayer + ((size_t)i << 10);
        w.a[j] = (i > 0)       ? row[i - 1] : 0.0f;
        w.b[j] = row[i];
        w.c[j] = (i < NYP - 1) ? row[i + 1] : 0.0f;
    }
}

__global__ __launch_bounds__(64) void propagate_direct(const float* __restrict__ x,
                                                       const float* __restrict__ W,
                                                       float* __restrict__ out) {
    const int b = blockIdx.x;
    const int lane = threadIdx.x & 63;
    const int i0 = lane * RPL;

    float h[RPL];
    const float4* xb = reinterpret_cast<const float4*>(x + (size_t)b * NYP + i0);
#pragma unroll
    for (int j = 0; j < RPL / 4; ++j) {
        float4 v = xb[j];
        h[4 * j + 0] = v.x; h[4 * j + 1] = v.y;
        h[4 * j + 2] = v.z; h[4 * j + 3] = v.w;
    }

    Wl w0, w1;
    load_layer_direct(W, i0, w0);
#pragma unroll 1
    for (int l = 0; l < NXL; l += 2) {
        load_layer_direct(W + ((size_t)(l + 1) << 20), i0, w1);
        step(h, w0);
        if (l + 2 < NXL) load_layer_direct(W + ((size_t)(l + 2) << 20), i0, w0);
        step(h, w1);
    }

    float4* ob = reinterpret_cast<float4*>(out + (size_t)b * NYP + i0);
#pragma unroll
    for (int j = 0; j < RPL / 4; ++j) {
        ob[j] = make_float4(h[4 * j + 0], h[4 * j + 1], h[4 * j + 2], h[4 * j + 3]);
    }
}

extern "C" void kernel_launch(void* const* d_in, const int* in_sizes, int n_in,
                              void* d_out, int out_size, void* d_ws, size_t ws_size,
                              hipStream_t stream) {
    const float* x = (const float*)d_in[0];   // [256,1024] f32
    const float* W = (const float*)d_in[1];   // [128,1024,1024] f32
    float* out = (float*)d_out;               // [256,1024] f32

    const size_t need = (size_t)NXL * 3 * NYP * sizeof(float);  // 1.5 MB
    if (ws_size >= need) {
        float* wb = (float*)d_ws;
        extract_band<<<(NXL * NYP) / 256, 256, 0, stream>>>(W, wb);
        propagate<<<NB, 64, 0, stream>>>(x, wb, out);
    } else {
        propagate_direct<<<NB, 64, 0, stream>>>(x, W, out);
    }
}